// Round 1
// baseline (369.712 us; speedup 1.0000x reference)
//
#include <hip/hip_runtime.h>

#define EPS 1e-6f

typedef _Float16 f16;
typedef _Float16 f16x8 __attribute__((ext_vector_type(8)));
typedef _Float16 f16x4 __attribute__((ext_vector_type(4)));
typedef float f32x4 __attribute__((ext_vector_type(4)));

__device__ __forceinline__ float tanh_fast(float x) {
    // tanh(x) = 1 - 2/(e^{2x}+1); exact at +-inf, ~1e-7 rel err
    float e = __expf(2.0f * x);
    return 1.0f - 2.0f / (e + 1.0f);
}

// ---------------- kernel 1: convert W1, W4 to f16 copies in ws ----------------
__global__ __launch_bounds__(256) void wconv_kernel(
    const float* __restrict__ W1, const float* __restrict__ W4,
    f16* __restrict__ W1h, f16* __restrict__ W4h)
{
    int gid = blockIdx.x * 256 + threadIdx.x;     // 0..131071
    const float4* s1 = (const float4*)W1;
    const float4* s4 = (const float4*)W4;
    f16x4* d1 = (f16x4*)W1h;
    f16x4* d4 = (f16x4*)W4h;
    #pragma unroll
    for (int r = 0; r < 2; ++r) {
        int i = gid + r * 131072;                 // < 262144 float4 per matrix
        float4 v = s1[i];
        f16x4 o; o[0]=(f16)v.x; o[1]=(f16)v.y; o[2]=(f16)v.z; o[3]=(f16)v.w;
        d1[i] = o;
        float4 u = s4[i];
        f16x4 p; p[0]=(f16)u.x; p[1]=(f16)u.y; p[2]=(f16)u.z; p[3]=(f16)u.w;
        d4[i] = p;
    }
}

// ---------------- kernel 2: gamma = tanh(input@W2^T+b2), alpha = tanh(input@W5^T+b5) ----------------
__global__ __launch_bounds__(256) void gamal_kernel(
    const float* __restrict__ inp,
    const float* __restrict__ W2, const float* __restrict__ b2,
    const float* __restrict__ W5, const float* __restrict__ b5,
    float* __restrict__ gamm, float* __restrict__ alph)
{
    const float* W  = blockIdx.y ? W5 : W2;
    const float* bs = blockIdx.y ? b5 : b2;
    float* dst      = blockIdx.y ? alph : gamm;
    int wid = threadIdx.x >> 6, lane = threadIdx.x & 63;
    int p = blockIdx.x * 4 + wid;                 // 0..65535
    int b = p >> 10, h = p & 1023;
    const float4* wr = (const float4*)(W + (size_t)h * 1024);
    const float4* xr = (const float4*)(inp + (size_t)b * 1024);
    float acc = 0.f;
    #pragma unroll
    for (int j = 0; j < 4; ++j) {
        float4 w4 = wr[lane + 64 * j];
        float4 x4 = xr[lane + 64 * j];
        acc += w4.x * x4.x + w4.y * x4.y + w4.z * x4.z + w4.w * x4.w;
    }
    #pragma unroll
    for (int o = 32; o; o >>= 1) acc += __shfl_xor(acc, o);
    if (lane == 0) dst[p] = tanh_fast(acc + bs[h]);
}

// ---------------- kernel 3: fused  z = A@W^T,  logit[m] = sum_h tanh(z+bias)*gam ----------------
// A: [32768,1024] f32 (rows m = b*512+s).  W(f16): [1024,1024] (row h contiguous in k).
// Block: 128 rows x full H (internal loop over 4 chunks of 256 cols). 4 waves, each 64x128.
__global__ __launch_bounds__(256, 2) void fused_logits_kernel(
    const float* __restrict__ Ahid, const float* __restrict__ Afld,
    const f16* __restrict__ W1h, const f16* __restrict__ W4h,
    const float* __restrict__ b1, const float* __restrict__ b4,
    const float* __restrict__ gamm, const float* __restrict__ alph,
    float* __restrict__ Lh, float* __restrict__ Lf)
{
    const int mat = blockIdx.y;
    const float* A  = mat ? Afld : Ahid;
    const f16* W    = mat ? W4h : W1h;
    const float* bv = mat ? b4 : b1;
    const float* gv = mat ? alph : gamm;
    float* Lg       = mat ? Lf : Lh;

    const int m0 = blockIdx.x << 7;     // 128 rows per block
    const int bidx = m0 >> 9;           // batch index (128 | 512)
    const int t = threadIdx.x;
    const int lane = t & 63;
    const int wid = t >> 6;
    const int wr = wid >> 1, wc = wid & 1;

    __shared__ __align__(16) f16 aL[2][128 * 40];   // padded rows: 32 data + 8 pad
    __shared__ __align__(16) f16 wL[2][256 * 40];
    __shared__ float rowpart[128][2];

    if (t < 128) { rowpart[t][0] = 0.0f; rowpart[t][1] = 0.0f; }

    const int arow = t >> 1, ahalf = t & 1;
    const float* aG = A + (size_t)(m0 + arow) * 1024 + ahalf * 16;
    f16* aD0 = &aL[0][arow * 40 + ahalf * 16];
    f16* aD1 = &aL[1][arow * 40 + ahalf * 16];
    f16* wD0 = &wL[0][t * 40];
    f16* wD1 = &wL[1][t * 40];

    const int c16 = lane & 15;
    const int rq = lane >> 4;
    const int ks = rq << 3;
    const int rbase = (wr << 6) + c16;
    const int wbase = (wc << 7) + c16;

    f32x4 acc[4][8];

    for (int nc = 0; nc < 4; ++nc) {
        const f16* wG = W + (size_t)((nc << 8) + t) * 1024;
        f32x4 zz = {0.f, 0.f, 0.f, 0.f};
        #pragma unroll
        for (int mi = 0; mi < 4; ++mi)
            #pragma unroll
            for (int ni = 0; ni < 8; ++ni) acc[mi][ni] = zz;

        auto stage = [&](int kk, int buf) {
            const float4* ap = (const float4*)(aG + kk * 32);
            float4 x0 = ap[0], x1 = ap[1], x2 = ap[2], x3 = ap[3];
            const f16x8* wp = (const f16x8*)(wG + kk * 32);
            f16x8 w0 = wp[0], w1 = wp[1], w2 = wp[2], w3 = wp[3];
            f16x8 p0, p1;
            p0[0]=(f16)x0.x; p0[1]=(f16)x0.y; p0[2]=(f16)x0.z; p0[3]=(f16)x0.w;
            p0[4]=(f16)x1.x; p0[5]=(f16)x1.y; p0[6]=(f16)x1.z; p0[7]=(f16)x1.w;
            p1[0]=(f16)x2.x; p1[1]=(f16)x2.y; p1[2]=(f16)x2.z; p1[3]=(f16)x2.w;
            p1[4]=(f16)x3.x; p1[5]=(f16)x3.y; p1[6]=(f16)x3.z; p1[7]=(f16)x3.w;
            f16* ad = buf ? aD1 : aD0;
            f16* wd = buf ? wD1 : wD0;
            *(f16x8*)(ad)      = p0;
            *(f16x8*)(ad + 8)  = p1;
            *(f16x8*)(wd)      = w0;
            *(f16x8*)(wd + 8)  = w1;
            *(f16x8*)(wd + 16) = w2;
            *(f16x8*)(wd + 24) = w3;
        };

        stage(0, 0);
        __syncthreads();

        for (int kk = 0; kk < 32; ++kk) {
            const int cur = kk & 1;
            if (kk < 31) stage(kk + 1, cur ^ 1);
            const f16* aB = aL[cur];
            const f16* wB = wL[cur];
            f16x8 af[4];
            #pragma unroll
            for (int mi = 0; mi < 4; ++mi)
                af[mi] = *(const f16x8*)&aB[(rbase + mi * 16) * 40 + ks];
            #pragma unroll
            for (int ni = 0; ni < 8; ++ni) {
                f16x8 bf = *(const f16x8*)&wB[(wbase + ni * 16) * 40 + ks];
                #pragma unroll
                for (int mi = 0; mi < 4; ++mi)
                    acc[mi][ni] = __builtin_amdgcn_mfma_f32_16x16x32_f16(af[mi], bf, acc[mi][ni], 0, 0, 0);
            }
            __syncthreads();
        }

        // epilogue: tanh + gamma-dot, reduce over this 256-col chunk
        float g[8], bb[8];
        #pragma unroll
        for (int ni = 0; ni < 8; ++ni) {
            int h = (nc << 8) + (wc << 7) + ni * 16 + c16;
            g[ni]  = gv[(bidx << 10) + h];
            bb[ni] = bv[h];
        }
        #pragma unroll
        for (int mi = 0; mi < 4; ++mi) {
            float v0 = 0.f, v1 = 0.f, v2 = 0.f, v3 = 0.f;
            #pragma unroll
            for (int ni = 0; ni < 8; ++ni) {
                v0 += tanh_fast(acc[mi][ni][0] + bb[ni]) * g[ni];
                v1 += tanh_fast(acc[mi][ni][1] + bb[ni]) * g[ni];
                v2 += tanh_fast(acc[mi][ni][2] + bb[ni]) * g[ni];
                v3 += tanh_fast(acc[mi][ni][3] + bb[ni]) * g[ni];
            }
            #pragma unroll
            for (int off = 1; off < 16; off <<= 1) {
                v0 += __shfl_xor(v0, off);
                v1 += __shfl_xor(v1, off);
                v2 += __shfl_xor(v2, off);
                v3 += __shfl_xor(v3, off);
            }
            if (c16 == 0) {
                int rb = (wr << 6) + mi * 16 + (rq << 2);
                rowpart[rb + 0][wc] += v0;
                rowpart[rb + 1][wc] += v1;
                rowpart[rb + 2][wc] += v2;
                rowpart[rb + 3][wc] += v3;
            }
        }
    }
    __syncthreads();
    if (t < 128) Lg[m0 + t] = rowpart[t][0] + rowpart[t][1];
}

// ---------------- kernel 4: dual softmax over S + combine + renormalize ----------------
__device__ __forceinline__ float blockMax(float v, float* sm) {
    #pragma unroll
    for (int o = 32; o; o >>= 1) v = fmaxf(v, __shfl_xor(v, o));
    if ((threadIdx.x & 63) == 0) sm[threadIdx.x >> 6] = v;
    __syncthreads();
    v = fmaxf(fmaxf(sm[0], sm[1]), fmaxf(sm[2], sm[3]));
    __syncthreads();
    return v;
}
__device__ __forceinline__ float blockSum(float v, float* sm) {
    #pragma unroll
    for (int o = 32; o; o >>= 1) v += __shfl_xor(v, o);
    if ((threadIdx.x & 63) == 0) sm[threadIdx.x >> 6] = v;
    __syncthreads();
    v = sm[0] + sm[1] + sm[2] + sm[3];
    __syncthreads();
    return v;
}

__global__ __launch_bounds__(256) void softmax_combine_kernel(
    const float* __restrict__ Lh, const float* __restrict__ Lf,
    float* __restrict__ wfin, float* __restrict__ dout)
{
    __shared__ float sm[4];
    int b = blockIdx.x, t = threadIdx.x;
    float h0 = Lh[b * 512 + t], h1 = Lh[b * 512 + 256 + t];
    float f0 = Lf[b * 512 + t], f1 = Lf[b * 512 + 256 + t];
    float mh = blockMax(fmaxf(h0, h1), sm);
    float mf = blockMax(fmaxf(f0, f1), sm);
    float e0 = __expf(h0 - mh), e1 = __expf(h1 - mh);
    float q0 = __expf(f0 - mf), q1 = __expf(f1 - mf);
    float sh = blockSum(e0 + e1, sm);
    float sf = blockSum(q0 + q1, sm);
    float wh0 = e0 / (EPS + sh), wh1 = e1 / (EPS + sh);
    float wq0 = q0 / (EPS + sf), wq1 = q1 / (EPS + sf);
    float c0 = wh0 * wq0, c1 = wh1 * wq1;
    float sc = blockSum(c0 + c1, sm);
    float r0 = c0 / (EPS + sc), r1 = c1 / (EPS + sc);
    wfin[b * 512 + t]       = r0;
    wfin[b * 512 + 256 + t] = r1;
    dout[65536 + t * 64 + b]         = r0;   // weights output: [S,B,1], s-major
    dout[65536 + (256 + t) * 64 + b] = r1;
}

// ---------------- kernel 5: context partials  ctxpart[sh][b,d] = sum_{s in half} hs*w ----------------
__global__ __launch_bounds__(256) void context_kernel(
    const float* __restrict__ hs, const float* __restrict__ wgt,
    float* __restrict__ ctxpart)
{
    int dq = blockIdx.x;   // 0..3  (256 floats of D each)
    int b  = blockIdx.y;   // 0..63
    int sh = blockIdx.z;   // 0..1  (256 s each)
    int t = threadIdx.x;
    int ss = t >> 6, ds = t & 63;
    __shared__ float4 part[4][64];
    const float4* hp = (const float4*)hs;
    float ax = 0.f, ay = 0.f, az = 0.f, aw = 0.f;
    int sBase = sh * 256 + ss * 64;
    for (int i = 0; i < 64; ++i) {
        int s = sBase + i;
        float w = wgt[b * 512 + s];
        float4 v = hp[(size_t)(b * 512 + s) * 256 + dq * 64 + ds];
        ax += v.x * w; ay += v.y * w; az += v.z * w; aw += v.w * w;
    }
    float4 r; r.x = ax; r.y = ay; r.z = az; r.w = aw;
    part[ss][ds] = r;
    __syncthreads();
    if (ss == 0) {
        float4 a0 = part[0][ds], a1 = part[1][ds], a2 = part[2][ds], a3 = part[3][ds];
        float4 o;
        o.x = a0.x + a1.x + a2.x + a3.x;
        o.y = a0.y + a1.y + a2.y + a3.y;
        o.z = a0.z + a1.z + a2.z + a3.z;
        o.w = a0.w + a1.w + a2.w + a3.w;
        ((float4*)ctxpart)[(size_t)sh * 16384 + b * 256 + dq * 64 + ds] = o;
    }
}

// ---------------- kernel 6: out = [context|input] @ W3^T + b3, masked by finished ----------------
__global__ __launch_bounds__(256) void out_kernel(
    const float* __restrict__ ctxpart, const float* __restrict__ inp,
    const float* __restrict__ W3, const float* __restrict__ b3,
    const unsigned char* __restrict__ fin, float* __restrict__ out)
{
    int t = threadIdx.x, wid = t >> 6, lane = t & 63;
    int h = blockIdx.x * 4 + wid;
    __shared__ __align__(16) float xs[2048];
    float4* xsv = (float4*)xs;
    float4 wreg[8];
    const float4* w3r = (const float4*)(W3 + (size_t)h * 2048);
    #pragma unroll
    for (int j = 0; j < 8; ++j) wreg[j] = w3r[lane + 64 * j];
    const float4* cp = (const float4*)ctxpart;   // [2][16384] float4 view
    const float4* xp = (const float4*)inp;
    for (int b = 0; b < 64; ++b) {
        __syncthreads();
        {
            float4 c0 = cp[b * 256 + t];
            float4 c1 = cp[16384 + b * 256 + t];
            float4 cc; cc.x = c0.x + c1.x; cc.y = c0.y + c1.y;
            cc.z = c0.z + c1.z; cc.w = c0.w + c1.w;
            xsv[t] = cc;                 // k4 0..255  = context
            xsv[256 + t] = xp[b * 256 + t];   // k4 256..511 = input
        }
        __syncthreads();
        float acc = 0.f;
        #pragma unroll
        for (int j = 0; j < 8; ++j) {
            float4 x = xsv[lane + 64 * j];
            acc += wreg[j].x * x.x + wreg[j].y * x.y + wreg[j].z * x.z + wreg[j].w * x.w;
        }
        #pragma unroll
        for (int o = 32; o; o >>= 1) acc += __shfl_xor(acc, o);
        if (lane == 0) out[b * 1024 + h] = fin[b] ? 0.f : (acc + b3[h]);
    }
}

extern "C" void kernel_launch(void* const* d_in, const int* in_sizes, int n_in,
                              void* d_out, int out_size, void* d_ws, size_t ws_size,
                              hipStream_t stream)
{
    const float* hidden = (const float*)d_in[0];
    const float* field  = (const float*)d_in[1];
    const float* input  = (const float*)d_in[2];
    const unsigned char* fin = (const unsigned char*)d_in[3];
    const float* W1 = (const float*)d_in[4];
    const float* b1 = (const float*)d_in[5];
    const float* W2 = (const float*)d_in[6];
    const float* b2 = (const float*)d_in[7];
    const float* W3 = (const float*)d_in[8];
    const float* b3 = (const float*)d_in[9];
    const float* W4 = (const float*)d_in[10];
    const float* b4 = (const float*)d_in[11];
    const float* W5 = (const float*)d_in[12];
    const float* b5 = (const float*)d_in[13];
    float* out = (float*)d_out;

    char* ws = (char*)d_ws;
    float* Lh   = (float*)(ws);              // 32768 f32
    float* Lf   = (float*)(ws + 131072);     // 32768 f32
    float* wfin = (float*)(ws + 262144);     // 32768 f32
    float* gamm = (float*)(ws + 393216);     // 65536 f32
    float* alph = (float*)(ws + 655360);     // 65536 f32
    float* ctxp = (float*)(ws + 917504);     // 2*65536 f32
    f16*   W1h  = (f16*)(ws + 1441792);      // 1048576 f16
    f16*   W4h  = (f16*)(ws + 3538944);      // 1048576 f16

    wconv_kernel<<<512, 256, 0, stream>>>(W1, W4, W1h, W4h);
    gamal_kernel<<<dim3(16384, 2), 256, 0, stream>>>(input, W2, b2, W5, b5, gamm, alph);
    fused_logits_kernel<<<dim3(256, 2), 256, 0, stream>>>(hidden, field, W1h, W4h,
                                                          b1, b4, gamm, alph, Lh, Lf);
    softmax_combine_kernel<<<64, 256, 0, stream>>>(Lh, Lf, wfin, out);
    context_kernel<<<dim3(4, 64, 2), 256, 0, stream>>>(hidden, wfin, ctxp);
    out_kernel<<<256, 256, 0, stream>>>(ctxp, input, W3, b3, fin, out);
}